// Round 2
// baseline (6765.437 us; speedup 1.0000x reference)
//
#include <hip/hip_runtime.h>
#include <math.h>

// G=128, S=32, P=16, D=768, C=256, NH=4, OUT=7; NR = G*P = 2048
#define NG 128
#define NS 32
#define NP 16
#define ND 768
#define NC 256
#define NHD 4
#define NOUT 7
#define NR 2048

typedef unsigned short ushortT;
typedef short bf16x8 __attribute__((ext_vector_type(8)));
typedef float f32x4 __attribute__((ext_vector_type(4)));

__device__ __forceinline__ ushortT f2b(float f) {
    union { float f; unsigned u; } v; v.f = f;
    unsigned r = (v.u + 0x7FFF + ((v.u >> 16) & 1)) >> 16;
    return (ushortT)r;
}
__device__ __forceinline__ float b2f(ushortT u) {
    union { unsigned u; float f; } v; v.u = ((unsigned)u) << 16; return v.f;
}
__device__ __forceinline__ float sigf(float v) { return 1.f / (1.f + expf(-v)); }

#define MFMA16(a, b, c) __builtin_amdgcn_mfma_f32_16x16x32_bf16((a), (b), (c), 0, 0, 0)

// ---------------------------------------------------------------------------
// Persistent per-graph mega-kernel: one block per graph runs the whole 32-step
// recurrence with all state (h carry, m, GAT output) in LDS/registers.
// 128 blocks x 512 threads (8 waves). Weights streamed from L2 each step.
// ---------------------------------------------------------------------------
__global__ __launch_bounds__(512, 2) void mega_kernel(
    const float* __restrict__ x,
    const ushortT* __restrict__ WihB, const ushortT* __restrict__ WhhB,
    const ushortT* __restrict__ WcombB, const float* __restrict__ bcomb,
    const ushortT* __restrict__ gatB, const ushortT* __restrict__ WusB,
    const float* __restrict__ busv,
    const float* __restrict__ bih, const float* __restrict__ bhh,
    const float* __restrict__ att_src, const float* __restrict__ att_dst,
    const float* __restrict__ gat_b, const float* __restrict__ attW,
    const float* __restrict__ attb, const float* __restrict__ clsW,
    const float* __restrict__ clsb, float* __restrict__ outp)
{
    __shared__ float hb[16][1032];        // GAT-transformed rows (f32), 1024+pad
    __shared__ float m_f[16][264];        // memory state m (f32), 256+pad
    __shared__ ushortT hrun_b[16][264];   // bf16 image of h_run carry
    __shared__ ushortT hnxt_b[16][264];   // bf16 h_nxt
    __shared__ ushortT spk_b[800];        // bf16 speaker vec (768)
    __shared__ float ats_s[1024], atd_s[1024], gatb_s[256];
    __shared__ float es_s[16][4], ed_s[16][4], gate_s[16], pooled_s[256];

    const int g = blockIdx.x, tid = threadIdx.x;
    const int w = tid >> 6, lane = tid & 63;
    const int quad = lane >> 4, l15 = lane & 15;

    for (int i = tid; i < 1024; i += 512) { ats_s[i] = att_src[i]; atd_s[i] = att_dst[i]; }
    for (int i = tid; i < 256; i += 512) gatb_s[i] = gat_b[i];
    for (int i = tid; i < 16 * 264; i += 512) ((ushortT*)hrun_b)[i] = 0;
    float hreg[2][4];   // f32 h_run carry: wave w owns cols w*32+nt*16+l15, rows quad*4+r
#pragma unroll
    for (int nt = 0; nt < 2; ++nt)
#pragma unroll
        for (int r = 0; r < 4; ++r) hreg[nt][r] = 0.f;
    __syncthreads();

    // ---- fused GAT-softmax + pool + classify; reads hb, writes m_f + outp ----
    auto fin = [&](int s) {
        // part1: es/ed per node
        for (int p = w; p < 16; p += 8) {
            const float* row = hb[p];
            float ss[4] = {0.f, 0.f, 0.f, 0.f}, sd[4] = {0.f, 0.f, 0.f, 0.f};
#pragma unroll
            for (int i = 0; i < 16; ++i) {
                const int col = lane + 64 * i;
                const float v = row[col];
                ss[i >> 2] += v * ats_s[col];
                sd[i >> 2] += v * atd_s[col];
            }
            for (int off = 32; off; off >>= 1)
#pragma unroll
                for (int h = 0; h < 4; ++h) {
                    ss[h] += __shfl_down(ss[h], off);
                    sd[h] += __shfl_down(sd[h], off);
                }
            if (lane == 0)
#pragma unroll
                for (int h = 0; h < 4; ++h) { es_s[p][h] = ss[h]; ed_s[p][h] = sd[h]; }
        }
        __syncthreads();
        // part2: edge softmax + head mean -> m
        {
            const int p = tid >> 5, cb = (tid & 31) * 8;
            float accv[8];
#pragma unroll
            for (int cj = 0; cj < 8; ++cj) accv[cj] = 0.f;
#pragma unroll
            for (int h = 0; h < 4; ++h) {
                float e1 = es_s[0][h] + ed_s[p][h]; e1 = e1 > 0.f ? e1 : 0.2f * e1;
                float e2 = es_s[p][h] + ed_s[p][h]; e2 = e2 > 0.f ? e2 : 0.2f * e2;
                const float mx = fmaxf(e1, e2);
                float w0 = expf(e1 - mx), w1 = expf(e2 - mx);
                const float inv = 1.f / (w0 + w1);
                w0 *= inv; w1 *= inv;
                const float* r0 = &hb[0][h * NC + cb];
                const float* rp = &hb[p][h * NC + cb];
#pragma unroll
                for (int cj = 0; cj < 8; ++cj) accv[cj] += w0 * r0[cj] + w1 * rp[cj];
            }
#pragma unroll
            for (int cj = 0; cj < 8; ++cj)
                m_f[p][cb + cj] = accv[cj] * 0.25f + gatb_s[cb + cj];
        }
        __syncthreads();
        // part3: gate scores
        for (int p = w; p < 16; p += 8) {
            float sg = 0.f;
#pragma unroll
            for (int i = 0; i < 4; ++i) { const int c = lane + 64 * i; sg += m_f[p][c] * attW[c]; }
            for (int off = 32; off; off >>= 1) sg += __shfl_down(sg, off);
            if (lane == 0) gate_s[p] = sg + attb[0];
        }
        __syncthreads();
        // part4: softmax over nodes + pooled
        if (tid < 256) {
            float mx = -1e30f;
#pragma unroll
            for (int p = 0; p < 16; ++p) mx = fmaxf(mx, gate_s[p]);
            float se = 0.f, pc = 0.f;
#pragma unroll
            for (int p = 0; p < 16; ++p) {
                const float e = expf(gate_s[p] - mx);
                se += e; pc += e * m_f[p][tid];
            }
            pooled_s[tid] = pc / se;
        }
        __syncthreads();
        // part5: classify
        if (w < NOUT) {
            float a = 0.f;
#pragma unroll
            for (int i = 0; i < 4; ++i) {
                const int c = lane + 64 * i;
                a += pooled_s[c] * clsW[w * NC + c];
            }
            for (int off = 32; off; off >>= 1) a += __shfl_down(a, off);
            if (lane == 0) outp[((size_t)g * NS + s) * NOUT + w] = a + clsb[w];
        }
        __syncthreads();
    };

    // ---- step 0: hb = x[g,0] @ gatW (K=768), then fin(0) ----
    {
        const float* xg = x + (size_t)g * (NS * NP * ND);
        f32x4 a0[8];
#pragma unroll
        for (int t = 0; t < 8; ++t) a0[t] = (f32x4){0.f, 0.f, 0.f, 0.f};
        for (int kk = 0; kk < ND; kk += 32) {
            const float* ap = xg + (size_t)l15 * ND + kk + quad * 8;
            bf16x8 af;
#pragma unroll
            for (int i = 0; i < 8; ++i) af[i] = (short)f2b(ap[i]);
#pragma unroll
            for (int t = 0; t < 8; ++t) {
                const int col = w * 128 + t * 16 + l15;
                bf16x8 bv = *(const bf16x8*)(gatB + (size_t)col * ND + kk + quad * 8);
                a0[t] = MFMA16(af, bv, a0[t]);
            }
        }
#pragma unroll
        for (int t = 0; t < 8; ++t) {
            const int col = w * 128 + t * 16 + l15;
#pragma unroll
            for (int r = 0; r < 4; ++r) hb[quad * 4 + r][col] = a0[t][r];
        }
    }
    __syncthreads();
    fin(0);

    // ---- steps 1..31 ----
    for (int j = 1; j < NS; ++j) {
        // === gru1: gi = m@Wih^T, gh = h@Whh^T; update h_run (regs + hrun_b) ===
        {
            f32x4 a1[2][3][2];
#pragma unroll
            for (int mm = 0; mm < 2; ++mm)
#pragma unroll
                for (int gt = 0; gt < 3; ++gt)
#pragma unroll
                    for (int nt = 0; nt < 2; ++nt) a1[mm][gt][nt] = (f32x4){0.f, 0.f, 0.f, 0.f};
            for (int kk = 0; kk < NC; kk += 32) {
                const float* mp = &m_f[l15][kk + quad * 8];
                bf16x8 afm;
#pragma unroll
                for (int i = 0; i < 8; ++i) afm[i] = (short)f2b(mp[i]);
                bf16x8 afh = *(const bf16x8*)&hrun_b[l15][kk + quad * 8];
#pragma unroll
                for (int gt = 0; gt < 3; ++gt)
#pragma unroll
                    for (int nt = 0; nt < 2; ++nt) {
                        const int col = gt * 256 + w * 32 + nt * 16 + l15;
                        bf16x8 b1 = *(const bf16x8*)(WihB + (size_t)col * NC + kk + quad * 8);
                        bf16x8 b2 = *(const bf16x8*)(WhhB + (size_t)col * NC + kk + quad * 8);
                        a1[0][gt][nt] = MFMA16(afm, b1, a1[0][gt][nt]);
                        a1[1][gt][nt] = MFMA16(afh, b2, a1[1][gt][nt]);
                    }
            }
            __syncthreads();   // all A-reads of hrun_b done before overwrite
#pragma unroll
            for (int nt = 0; nt < 2; ++nt) {
                const int c = w * 32 + nt * 16 + l15;
                const float br = bih[c], bz = bih[256 + c], bn = bih[512 + c];
                const float cr = bhh[c], cz = bhh[256 + c], cn = bhh[512 + c];
#pragma unroll
                for (int r = 0; r < 4; ++r) {
                    const int row = quad * 4 + r;
                    const float rg = sigf(a1[0][0][nt][r] + br + a1[1][0][nt][r] + cr);
                    const float zg = sigf(a1[0][1][nt][r] + bz + a1[1][1][nt][r] + cz);
                    const float ng = tanhf(a1[0][2][nt][r] + bn + rg * (a1[1][2][nt][r] + cn));
                    const float hn = (1.f - zg) * ng + zg * hreg[nt][r];
                    hreg[nt][r] = hn;
                    hrun_b[row][c] = f2b(hn);
                }
            }
        }
        __syncthreads();

        // === gru2 (zero input): gh = h_run@Whh^T; h_nxt -> hnxt_b ===
        {
            f32x4 a2[3][2];
#pragma unroll
            for (int gt = 0; gt < 3; ++gt)
#pragma unroll
                for (int nt = 0; nt < 2; ++nt) a2[gt][nt] = (f32x4){0.f, 0.f, 0.f, 0.f};
            for (int kk = 0; kk < NC; kk += 32) {
                bf16x8 afh = *(const bf16x8*)&hrun_b[l15][kk + quad * 8];
#pragma unroll
                for (int gt = 0; gt < 3; ++gt)
#pragma unroll
                    for (int nt = 0; nt < 2; ++nt) {
                        const int col = gt * 256 + w * 32 + nt * 16 + l15;
                        bf16x8 b2 = *(const bf16x8*)(WhhB + (size_t)col * NC + kk + quad * 8);
                        a2[gt][nt] = MFMA16(afh, b2, a2[gt][nt]);
                    }
            }
#pragma unroll
            for (int nt = 0; nt < 2; ++nt) {
                const int c = w * 32 + nt * 16 + l15;
                const float br = bih[c], bz = bih[256 + c], bn = bih[512 + c];
                const float cr = bhh[c], cz = bhh[256 + c], cn = bhh[512 + c];
#pragma unroll
                for (int r = 0; r < 4; ++r) {
                    const int row = quad * 4 + r;
                    const float rg = sigf(br + a2[0][nt][r] + cr);
                    const float zg = sigf(bz + a2[1][nt][r] + cz);
                    const float ng = tanhf(bn + rg * (a2[2][nt][r] + cn));
                    const float hv = (1.f - zg) * ng + zg * hreg[nt][r];
                    hnxt_b[row][c] = f2b(hv);
                }
            }
        }
        __syncthreads();

        // === speaker vec: spk = relu(h_nxt[0] @ Wus^T + bus), 4 lanes/output ===
        for (int it = 0; it < 6; ++it) {
            const int slot = it * 512 + tid;
            const int o = slot >> 2, part = slot & 3;
            float s = 0.f;
#pragma unroll
            for (int k8 = 0; k8 < 8; ++k8) {
                const int k = part * 64 + k8 * 8;
                bf16x8 hv8 = *(const bf16x8*)&hnxt_b[0][k];
                bf16x8 wv8 = *(const bf16x8*)(WusB + (size_t)o * NC + k);
#pragma unroll
                for (int i = 0; i < 8; ++i) s += b2f((ushortT)hv8[i]) * b2f((ushortT)wv8[i]);
            }
            s += __shfl_down(s, 1);
            s += __shfl_down(s, 2);
            if (part == 0) spk_b[o] = f2b(fmaxf(s + busv[o], 0.f));
        }
        __syncthreads();

        // === GAT merged-K: hb[p>=1] = h_nxt@Wcomb + bcomb ; hb[0] = spk@gatW ===
        {
            f32x4 ag[8];
#pragma unroll
            for (int t = 0; t < 8; ++t) ag[t] = (f32x4){0.f, 0.f, 0.f, 0.f};
            // K-part 1 (K=256): rows 1..15 from h_nxt, row 0 zeroed
            for (int kk = 0; kk < NC; kk += 32) {
                bf16x8 af;
                if (l15 == 0) {
#pragma unroll
                    for (int i = 0; i < 8; ++i) af[i] = 0;
                } else {
                    af = *(const bf16x8*)&hnxt_b[l15][kk + quad * 8];
                }
#pragma unroll
                for (int t = 0; t < 8; ++t) {
                    const int col = w * 128 + t * 16 + l15;
                    bf16x8 bv = *(const bf16x8*)(WcombB + (size_t)col * NC + kk + quad * 8);
                    ag[t] = MFMA16(af, bv, ag[t]);
                }
            }
            // K-part 2 (K=768): row 0 = spk, rows 1..15 zero
            for (int kk = 0; kk < ND; kk += 32) {
                bf16x8 af;
                if (l15 == 0) {
                    af = *(const bf16x8*)&spk_b[kk + quad * 8];
                } else {
#pragma unroll
                    for (int i = 0; i < 8; ++i) af[i] = 0;
                }
#pragma unroll
                for (int t = 0; t < 8; ++t) {
                    const int col = w * 128 + t * 16 + l15;
                    bf16x8 bv = *(const bf16x8*)(gatB + (size_t)col * ND + kk + quad * 8);
                    ag[t] = MFMA16(af, bv, ag[t]);
                }
            }
#pragma unroll
            for (int t = 0; t < 8; ++t) {
                const int col = w * 128 + t * 16 + l15;
                const float bc = bcomb[col];
#pragma unroll
                for (int r = 0; r < 4; ++r) {
                    const int row = quad * 4 + r;
                    hb[row][col] = ag[t][r] + (row ? bc : 0.f);
                }
            }
        }
        __syncthreads();

        fin(j);
    }
}

// ---------------------------------------------------------------------------
// Generic bf16 MFMA GEMM (prep only: Wcomb = gatW^T @ upW). 64x64 tile.
// ---------------------------------------------------------------------------
__global__ __launch_bounds__(256) void bgemm_kernel(
    const ushortT* __restrict__ A, const ushortT* __restrict__ Bt,
    ushortT* __restrict__ outH, int N, int K)
{
    __shared__ short As[64 * 40];
    __shared__ short Bs[64 * 40];
    const int tid = threadIdx.x;
    const int lane = tid & 63, wid = tid >> 6;
    const int quad = lane >> 4, l15 = lane & 15;
    const int row0 = blockIdx.y * 64, col0 = blockIdx.x * 64;
    const int mh = (wid & 1) * 32, nh = (wid >> 1) * 32;
    const int sr = tid >> 2, skq = (tid & 3) * 8;
    const ushortT* aptr = A + (size_t)(row0 + sr) * K;
    const ushortT* bptr = Bt + (size_t)(col0 + sr) * K;

    f32x4 acc[2][2];
    for (int i = 0; i < 2; ++i)
        for (int j = 0; j < 2; ++j) acc[i][j] = (f32x4){0.f, 0.f, 0.f, 0.f};

    for (int kk = 0; kk < K; kk += 32) {
        __syncthreads();
        *(uint4*)&As[sr * 40 + skq] = *(const uint4*)(aptr + kk + skq);
        *(uint4*)&Bs[sr * 40 + skq] = *(const uint4*)(bptr + kk + skq);
        __syncthreads();
        bf16x8 af0 = *(const bf16x8*)&As[(mh + l15) * 40 + quad * 8];
        bf16x8 af1 = *(const bf16x8*)&As[(mh + 16 + l15) * 40 + quad * 8];
        bf16x8 bf0 = *(const bf16x8*)&Bs[(nh + l15) * 40 + quad * 8];
        bf16x8 bf1 = *(const bf16x8*)&Bs[(nh + 16 + l15) * 40 + quad * 8];
        acc[0][0] = MFMA16(af0, bf0, acc[0][0]);
        acc[0][1] = MFMA16(af0, bf1, acc[0][1]);
        acc[1][0] = MFMA16(af1, bf0, acc[1][0]);
        acc[1][1] = MFMA16(af1, bf1, acc[1][1]);
    }
#pragma unroll
    for (int mt = 0; mt < 2; ++mt)
#pragma unroll
        for (int nt = 0; nt < 2; ++nt) {
            const int gc = col0 + nh + nt * 16 + l15;
#pragma unroll
            for (int r = 0; r < 4; ++r) {
                const int gr = row0 + mh + mt * 16 + quad * 4 + r;
                outH[(size_t)gr * N + gc] = f2b(acc[mt][nt][r]);
            }
        }
}

// ---------------------------------------------------------------------------
// Prep kernels
// ---------------------------------------------------------------------------
__global__ __launch_bounds__(256) void cast_kernel(const float* __restrict__ a,
                                                   ushortT* __restrict__ b, int n) {
    const int i = blockIdx.x * 256 + threadIdx.x;
    if (i < n) b[i] = f2b(a[i]);
}
__global__ __launch_bounds__(256) void gatT_kernel(const float* __restrict__ gW,
                                                   ushortT* __restrict__ gB) {
    const int idx = blockIdx.x * 256 + threadIdx.x; // < 1024*768
    const int c = idx / ND, d = idx - c * ND;
    gB[idx] = f2b(gW[(size_t)d * (NHD * NC) + c]);
}
// upWT_B[k][d] = up_W[d][k]  (bf16, [256][768])
__global__ __launch_bounds__(256) void upwT_kernel(const float* __restrict__ upW,
                                                   ushortT* __restrict__ o) {
    const int idx = blockIdx.x * 256 + threadIdx.x; // < 256*768
    const int k = idx / ND, d = idx - k * ND;
    o[idx] = f2b(upW[(size_t)d * NC + k]);
}
// bcomb[c] = sum_d up_b[d] * gatW[d][c]
__global__ __launch_bounds__(256) void bcomb_kernel(const float* __restrict__ gW,
                                                    const float* __restrict__ up_b,
                                                    float* __restrict__ bc) {
    const int c = blockIdx.x * 256 + threadIdx.x;
    if (c >= NHD * NC) return;
    float a = 0.f;
    for (int d = 0; d < ND; ++d) a += up_b[d] * gW[(size_t)d * (NHD * NC) + c];
    bc[c] = a;
}
__global__ __launch_bounds__(256) void spwc_kernel(const float* __restrict__ spW,
                                                   float* __restrict__ o) {
    const int idx = blockIdx.x * 256 + threadIdx.x; // < 768*768
    const int r = idx / ND, d = idx - r * ND;
    o[idx] = spW[(size_t)r * (2 * ND) + d] + spW[(size_t)r * (2 * ND) + ND + d];
}
// WusB[o][c] = sum_d spWc[o][d] * upW[d][c]  (bf16 out, BT layout [768][256])
__global__ __launch_bounds__(256) void wus_kernel(const float* __restrict__ spWc,
                                                  const float* __restrict__ upW,
                                                  ushortT* __restrict__ WusB) {
    const int c = threadIdx.x;
    const int o0 = blockIdx.x * 16;
    float acc[16];
#pragma unroll
    for (int i = 0; i < 16; ++i) acc[i] = 0.f;
    for (int d = 0; d < ND; ++d) {
        const float u = upW[(size_t)d * NC + c];
#pragma unroll
        for (int i = 0; i < 16; ++i) acc[i] += spWc[(size_t)(o0 + i) * ND + d] * u;
    }
#pragma unroll
    for (int i = 0; i < 16; ++i) WusB[(size_t)(o0 + i) * NC + c] = f2b(acc[i]);
}
__global__ __launch_bounds__(256) void bus_kernel(const float* __restrict__ spWc,
                                                  const float* __restrict__ up_b,
                                                  const float* __restrict__ sp_b,
                                                  float* __restrict__ bus) {
    const int o = blockIdx.x * 256 + threadIdx.x;
    if (o >= ND) return;
    float a = sp_b[o];
    const float* sr = spWc + (size_t)o * ND;
    for (int d = 0; d < ND; ++d) a += sr[d] * up_b[d];
    bus[o] = a;
}

// ---------------------------------------------------------------------------
extern "C" void kernel_launch(void* const* d_in, const int* in_sizes, int n_in,
                              void* d_out, int out_size, void* d_ws, size_t ws_size,
                              hipStream_t stream) {
    (void)in_sizes; (void)n_in; (void)out_size; (void)ws_size;
    const float* x       = (const float*)d_in[0];
    const float* gat_W   = (const float*)d_in[1];
    const float* att_src = (const float*)d_in[2];
    const float* att_dst = (const float*)d_in[3];
    const float* gat_b   = (const float*)d_in[4];
    const float* gru_Wih = (const float*)d_in[5];
    const float* gru_Whh = (const float*)d_in[6];
    const float* gru_bih = (const float*)d_in[7];
    const float* gru_bhh = (const float*)d_in[8];
    const float* up_W    = (const float*)d_in[9];
    const float* up_b    = (const float*)d_in[10];
    const float* sp_W    = (const float*)d_in[11];
    const float* sp_b    = (const float*)d_in[12];
    const float* att_W   = (const float*)d_in[13];
    const float* att_b   = (const float*)d_in[14];
    const float* cls_W   = (const float*)d_in[15];
    const float* cls_b   = (const float*)d_in[16];
    float* outp = (float*)d_out;

    char* w = (char*)d_ws;
    ushortT* WihB  = (ushortT*)w; w += (size_t)(3 * NC) * NC * 2;
    ushortT* WhhB  = (ushortT*)w; w += (size_t)(3 * NC) * NC * 2;
    ushortT* gatB  = (ushortT*)w; w += (size_t)(NHD * NC) * ND * 2;
    ushortT* upWT  = (ushortT*)w; w += (size_t)NC * ND * 2;
    ushortT* WcombB= (ushortT*)w; w += (size_t)(NHD * NC) * NC * 2;
    ushortT* WusB  = (ushortT*)w; w += (size_t)ND * NC * 2;
    float*   bcomb = (float*)w;   w += (size_t)(NHD * NC) * 4;
    float*   spWc  = (float*)w;   w += (size_t)ND * ND * 4;
    float*   bus   = (float*)w;   w += (size_t)ND * 4;

    // ---- weight prep ----
    cast_kernel<<<768, 256, 0, stream>>>(gru_Wih, WihB, 3 * NC * NC);
    cast_kernel<<<768, 256, 0, stream>>>(gru_Whh, WhhB, 3 * NC * NC);
    gatT_kernel<<<(NHD * NC * ND) / 256, 256, 0, stream>>>(gat_W, gatB);
    upwT_kernel<<<(NC * ND) / 256, 256, 0, stream>>>(up_W, upWT);
    bcomb_kernel<<<(NHD * NC) / 256, 256, 0, stream>>>(gat_W, up_b, bcomb);
    spwc_kernel<<<(ND * ND) / 256, 256, 0, stream>>>(sp_W, spWc);
    wus_kernel<<<ND / 16, 256, 0, stream>>>(spWc, up_W, WusB);
    bus_kernel<<<3, 256, 0, stream>>>(spWc, up_b, sp_b, bus);
    // Wcomb[c][k] = sum_d gatW[d][c] * upW[d][k]  -> bf16 Bt layout [1024][256]
    bgemm_kernel<<<dim3(NC / 64, (NHD * NC) / 64), 256, 0, stream>>>(
        gatB, upWT, WcombB, NC, ND);

    // ---- the whole recurrence: one block per graph ----
    mega_kernel<<<NG, 512, 0, stream>>>(
        x, WihB, WhhB, WcombB, bcomb, gatB, WusB, bus,
        gru_bih, gru_bhh, att_src, att_dst, gat_b,
        att_W, att_b, cls_W, cls_b, outp);
}

// Round 3
// 2957.958 us; speedup vs baseline: 2.2872x; 2.2872x over previous
//
#include <hip/hip_runtime.h>
#include <math.h>

// G=128, S=32, P=16, D=768, C=256, NH=4, OUT=7; NR = G*P = 2048
#define NG 128
#define NS 32
#define NP 16
#define ND 768
#define NC 256
#define NHD 4
#define NOUT 7
#define NR 2048

typedef unsigned short ushortT;
typedef short bf16x8 __attribute__((ext_vector_type(8)));
typedef float f32x4 __attribute__((ext_vector_type(4)));

__device__ __forceinline__ ushortT f2b(float f) {
    union { float f; unsigned u; } v; v.f = f;
    unsigned r = (v.u + 0x7FFF + ((v.u >> 16) & 1)) >> 16;
    return (ushortT)r;
}
__device__ __forceinline__ float b2f(ushortT u) {
    union { unsigned u; float f; } v; v.u = ((unsigned)u) << 16; return v.f;
}
__device__ __forceinline__ float sigf(float v) { return 1.f / (1.f + expf(-v)); }

#define MFMA16(a, b, c) __builtin_amdgcn_mfma_f32_16x16x32_bf16((a), (b), (c), 0, 0, 0)

// ---------------------------------------------------------------------------
// Kernel A: fused GRU step1 + step2 + speaker projection. One block = one
// graph (16 rows x 256 cols), 512 threads (8 waves, wave w -> cols w*32..+31).
// B matrices streamed through LDS in 48KB K-chunks (wide coalesced loads).
// ---------------------------------------------------------------------------
__global__ __launch_bounds__(512) void gru12spk_kernel(
    const ushortT* __restrict__ mB, const ushortT* __restrict__ hB,
    float* __restrict__ hF,
    const ushortT* __restrict__ WihB, const ushortT* __restrict__ WhhB,
    const ushortT* __restrict__ WusB,
    const float* __restrict__ bih, const float* __restrict__ bhh,
    const float* __restrict__ busv,
    ushortT* __restrict__ hBout, ushortT* __restrict__ hnB,
    ushortT* __restrict__ spkB)
{
    __shared__ short Am[16 * 264];   // m tile, later h_run bf16
    __shared__ short Ah[16 * 264];   // h_old tile, later h_nxt bf16
    __shared__ short Bs[768 * 40];   // staged B K-chunk (768 gate-cols x 32 k)
    const int g = blockIdx.x, tid = threadIdx.x;
    const int w = tid >> 6, lane = tid & 63;
    const int quad = lane >> 4, l15 = lane & 15;
    const int row0 = g * 16;

    {   // stage A tiles (one uint4 per thread each)
        const int row = tid >> 5, kc = (tid & 31) * 8;
        *(uint4*)&Am[row * 264 + kc] = *(const uint4*)(mB + (size_t)(row0 + row) * NC + kc);
        *(uint4*)&Ah[row * 264 + kc] = *(const uint4*)(hB + (size_t)(row0 + row) * NC + kc);
    }

    f32x4 ai[3][2], ah[3][2];
#pragma unroll
    for (int gt = 0; gt < 3; ++gt)
#pragma unroll
        for (int nf = 0; nf < 2; ++nf) {
            ai[gt][nf] = (f32x4){0.f, 0.f, 0.f, 0.f};
            ah[gt][nf] = (f32x4){0.f, 0.f, 0.f, 0.f};
        }

    // ---- pass 1: gi = m @ Wih^T ----
    for (int kk = 0; kk < NC; kk += 32) {
        __syncthreads();
        for (int s = tid; s < 3072; s += 512) {
            const int row = s >> 2, kq = (s & 3) * 8;
            *(uint4*)&Bs[row * 40 + kq] = *(const uint4*)(WihB + (size_t)row * NC + kk + kq);
        }
        __syncthreads();
        bf16x8 af = *(const bf16x8*)&Am[l15 * 264 + kk + quad * 8];
#pragma unroll
        for (int gt = 0; gt < 3; ++gt)
#pragma unroll
            for (int nf = 0; nf < 2; ++nf) {
                bf16x8 bv = *(const bf16x8*)&Bs[(gt * 256 + w * 32 + nf * 16 + l15) * 40 + quad * 8];
                ai[gt][nf] = MFMA16(af, bv, ai[gt][nf]);
            }
    }
    // ---- pass 2: gh = h_old @ Whh^T ----
    for (int kk = 0; kk < NC; kk += 32) {
        __syncthreads();
        for (int s = tid; s < 3072; s += 512) {
            const int row = s >> 2, kq = (s & 3) * 8;
            *(uint4*)&Bs[row * 40 + kq] = *(const uint4*)(WhhB + (size_t)row * NC + kk + kq);
        }
        __syncthreads();
        bf16x8 af = *(const bf16x8*)&Ah[l15 * 264 + kk + quad * 8];
#pragma unroll
        for (int gt = 0; gt < 3; ++gt)
#pragma unroll
            for (int nf = 0; nf < 2; ++nf) {
                bf16x8 bv = *(const bf16x8*)&Bs[(gt * 256 + w * 32 + nf * 16 + l15) * 40 + quad * 8];
                ah[gt][nf] = MFMA16(af, bv, ah[gt][nf]);
            }
    }
    // ---- gate math 1: h_run (f32 carry via hF) ----
    float hreg[2][4];
#pragma unroll
    for (int nf = 0; nf < 2; ++nf) {
        const int c = w * 32 + nf * 16 + l15;
        const float br = bih[c], bz = bih[256 + c], bn = bih[512 + c];
        const float cr = bhh[c], cz = bhh[256 + c], cn = bhh[512 + c];
#pragma unroll
        for (int r = 0; r < 4; ++r) {
            const int row = quad * 4 + r;
            const size_t idx = (size_t)(row0 + row) * NC + c;
            const float hold = hF[idx];
            const float rg = sigf(ai[0][nf][r] + br + ah[0][nf][r] + cr);
            const float zg = sigf(ai[1][nf][r] + bz + ah[1][nf][r] + cz);
            const float ng = tanhf(ai[2][nf][r] + bn + rg * (ah[2][nf][r] + cn));
            const float hn = (1.f - zg) * ng + zg * hold;
            hreg[nf][r] = hn;
            hF[idx] = hn;
            hBout[idx] = f2b(hn);
            Am[row * 264 + c] = (short)f2b(hn);   // h_run bf16 for pass 3
        }
    }
    // ---- pass 3: gh2 = h_run @ Whh^T ----
    f32x4 a2[3][2];
#pragma unroll
    for (int gt = 0; gt < 3; ++gt)
#pragma unroll
        for (int nf = 0; nf < 2; ++nf) a2[gt][nf] = (f32x4){0.f, 0.f, 0.f, 0.f};
    for (int kk = 0; kk < NC; kk += 32) {
        __syncthreads();
        for (int s = tid; s < 3072; s += 512) {
            const int row = s >> 2, kq = (s & 3) * 8;
            *(uint4*)&Bs[row * 40 + kq] = *(const uint4*)(WhhB + (size_t)row * NC + kk + kq);
        }
        __syncthreads();
        bf16x8 af = *(const bf16x8*)&Am[l15 * 264 + kk + quad * 8];
#pragma unroll
        for (int gt = 0; gt < 3; ++gt)
#pragma unroll
            for (int nf = 0; nf < 2; ++nf) {
                bf16x8 bv = *(const bf16x8*)&Bs[(gt * 256 + w * 32 + nf * 16 + l15) * 40 + quad * 8];
                a2[gt][nf] = MFMA16(af, bv, a2[gt][nf]);
            }
    }
    // ---- gate math 2: h_nxt ----
#pragma unroll
    for (int nf = 0; nf < 2; ++nf) {
        const int c = w * 32 + nf * 16 + l15;
        const float br = bih[c], bz = bih[256 + c], bn = bih[512 + c];
        const float cr = bhh[c], cz = bhh[256 + c], cn = bhh[512 + c];
#pragma unroll
        for (int r = 0; r < 4; ++r) {
            const int row = quad * 4 + r;
            const size_t idx = (size_t)(row0 + row) * NC + c;
            const float rg = sigf(br + a2[0][nf][r] + cr);
            const float zg = sigf(bz + a2[1][nf][r] + cz);
            const float ng = tanhf(bn + rg * (a2[2][nf][r] + cn));
            const float hv = (1.f - zg) * ng + zg * hreg[nf][r];
            const ushortT hb16 = f2b(hv);
            hnB[idx] = hb16;
            Ah[row * 264 + c] = (short)hb16;      // h_nxt bf16 for spk
        }
    }
    __syncthreads();
    // ---- speaker projection: spk = relu(h_nxt[row0] @ Wus^T + bus) ----
    for (int o = tid; o < ND; o += 512) {
        float s = busv[o];
        const ushortT* wr = WusB + (size_t)o * NC;
#pragma unroll 8
        for (int k8 = 0; k8 < 32; ++k8) {
            bf16x8 hv8 = *(const bf16x8*)&Ah[k8 * 8];          // row 0 (broadcast)
            bf16x8 wv8 = *(const bf16x8*)(wr + k8 * 8);
#pragma unroll
            for (int i = 0; i < 8; ++i) s += b2f((ushortT)hv8[i]) * b2f((ushortT)wv8[i]);
        }
        spkB[(size_t)g * ND + o] = f2b(fmaxf(s, 0.f));
    }
}

// ---------------------------------------------------------------------------
// Kernel B: main GAT GEMM (hnB@Wcomb+bcomb, non-speaker rows) + speaker
// overwrite GEMM (spkB@gatW, scatter stride 16). 544 blocks x 256 thr.
// ---------------------------------------------------------------------------
__global__ __launch_bounds__(256) void gatovr_kernel(
    const ushortT* __restrict__ hnB, const ushortT* __restrict__ spkB,
    const ushortT* __restrict__ WcombB, const ushortT* __restrict__ gatB,
    const float* __restrict__ bcomb, float* __restrict__ hbuf)
{
    __shared__ short As[64 * 40];
    __shared__ short Bs[64 * 40];
    const int b = blockIdx.x, tid = threadIdx.x;
    const int lane = tid & 63, wid = tid >> 6;
    const int quad = lane >> 4, l15 = lane & 15;
    const int mh = (wid & 1) * 32, nh = (wid >> 1) * 32;
    const int sr = tid >> 2, skq = (tid & 3) * 8;

    const bool ovr = (b >= 512);
    int row0, col0, K;
    const ushortT *A, *Bt;
    if (!ovr) {
        row0 = (b >> 4) * 64; col0 = (b & 15) * 64;
        A = hnB; Bt = WcombB; K = NC;
    } else {
        const int t = b - 512;
        row0 = (t & 1) * 64; col0 = (t >> 1) * 64;
        A = spkB; Bt = gatB; K = ND;
    }
    const ushortT* aptr = A + (size_t)(row0 + sr) * K;
    const ushortT* bptr = Bt + (size_t)(col0 + sr) * K;

    f32x4 acc[2][2];
    for (int i = 0; i < 2; ++i)
        for (int j = 0; j < 2; ++j) acc[i][j] = (f32x4){0.f, 0.f, 0.f, 0.f};

    for (int kk = 0; kk < K; kk += 32) {
        __syncthreads();
        *(uint4*)&As[sr * 40 + skq] = *(const uint4*)(aptr + kk + skq);
        *(uint4*)&Bs[sr * 40 + skq] = *(const uint4*)(bptr + kk + skq);
        __syncthreads();
        bf16x8 af0 = *(const bf16x8*)&As[(mh + l15) * 40 + quad * 8];
        bf16x8 af1 = *(const bf16x8*)&As[(mh + 16 + l15) * 40 + quad * 8];
        bf16x8 bf0 = *(const bf16x8*)&Bs[(nh + l15) * 40 + quad * 8];
        bf16x8 bf1 = *(const bf16x8*)&Bs[(nh + 16 + l15) * 40 + quad * 8];
        acc[0][0] = MFMA16(af0, bf0, acc[0][0]);
        acc[0][1] = MFMA16(af0, bf1, acc[0][1]);
        acc[1][0] = MFMA16(af1, bf0, acc[1][0]);
        acc[1][1] = MFMA16(af1, bf1, acc[1][1]);
    }
#pragma unroll
    for (int mt = 0; mt < 2; ++mt)
#pragma unroll
        for (int nt = 0; nt < 2; ++nt) {
            const int gc = col0 + nh + nt * 16 + l15;
            const float bv = ovr ? 0.f : bcomb[gc];
#pragma unroll
            for (int r = 0; r < 4; ++r) {
                const int gr = row0 + mh + mt * 16 + quad * 4 + r;
                const float v = acc[mt][nt][r] + bv;
                if (ovr) {
                    hbuf[(size_t)(gr * 16) * (NHD * NC) + gc] = v;
                } else if (gr & 15) {
                    hbuf[(size_t)gr * (NHD * NC) + gc] = v;
                }
            }
        }
}

// ---------------------------------------------------------------------------
// Fused GAT-softmax + head-mean + GlobalAttention pool + classifier.
// One block per graph. hbuf fp32 [2048][1024].
// ---------------------------------------------------------------------------
__global__ __launch_bounds__(256) void fin_kernel(
    const float* __restrict__ hbuf, const float* __restrict__ att_src,
    const float* __restrict__ att_dst, const float* __restrict__ gat_b,
    const float* __restrict__ attW, const float* __restrict__ attb,
    const float* __restrict__ clsW, const float* __restrict__ clsb,
    ushortT* __restrict__ mB, float* __restrict__ outp, int s)
{
    const int g = blockIdx.x, tid = threadIdx.x;
    const int lane = tid & 63, wid = tid >> 6;
    __shared__ float es_s[16][4], ed_s[16][4];
    __shared__ float m_s[16][260];
    __shared__ float gate_s[16];
    __shared__ float pooled_s[256];
    const float* hb = hbuf + (size_t)g * NP * (NHD * NC);

    for (int pi = 0; pi < 4; ++pi) {
        const int p = wid * 4 + pi;
        const float* row = hb + p * (NHD * NC);
        float ss[4] = {0.f, 0.f, 0.f, 0.f}, sd[4] = {0.f, 0.f, 0.f, 0.f};
#pragma unroll
        for (int i = 0; i < 16; ++i) {
            const int col = lane + 64 * i;
            const float v = row[col];
            ss[i >> 2] += v * att_src[col];
            sd[i >> 2] += v * att_dst[col];
        }
        for (int off = 32; off; off >>= 1)
#pragma unroll
            for (int h = 0; h < 4; ++h) {
                ss[h] += __shfl_down(ss[h], off);
                sd[h] += __shfl_down(sd[h], off);
            }
        if (lane == 0)
#pragma unroll
            for (int h = 0; h < 4; ++h) { es_s[p][h] = ss[h]; ed_s[p][h] = sd[h]; }
    }
    __syncthreads();
    {
        const int p = tid >> 4, cb = (tid & 15) * 16;
        float accv[16];
#pragma unroll
        for (int cj = 0; cj < 16; ++cj) accv[cj] = 0.f;
#pragma unroll
        for (int h = 0; h < 4; ++h) {
            float e1 = es_s[0][h] + ed_s[p][h]; e1 = e1 > 0.f ? e1 : 0.2f * e1;
            float e2 = es_s[p][h] + ed_s[p][h]; e2 = e2 > 0.f ? e2 : 0.2f * e2;
            const float mx = fmaxf(e1, e2);
            float w0 = expf(e1 - mx), w1 = expf(e2 - mx);
            const float inv = 1.f / (w0 + w1);
            w0 *= inv; w1 *= inv;
            const float* r0 = hb + h * NC + cb;
            const float* rp = hb + p * (NHD * NC) + h * NC + cb;
#pragma unroll
            for (int cj = 0; cj < 16; ++cj) accv[cj] += w0 * r0[cj] + w1 * rp[cj];
        }
#pragma unroll
        for (int cj = 0; cj < 16; ++cj) {
            const float v = accv[cj] * 0.25f + gat_b[cb + cj];
            m_s[p][cb + cj] = v;
            mB[(size_t)(g * NP + p) * NC + cb + cj] = f2b(v);
        }
    }
    __syncthreads();
    for (int pi = 0; pi < 4; ++pi) {
        const int p = wid * 4 + pi;
        float sg = 0.f;
#pragma unroll
        for (int i = 0; i < 4; ++i) { const int c = lane + 64 * i; sg += m_s[p][c] * attW[c]; }
        for (int off = 32; off; off >>= 1) sg += __shfl_down(sg, off);
        if (lane == 0) gate_s[p] = sg + attb[0];
    }
    __syncthreads();
    float mx = -1e30f;
#pragma unroll
    for (int p = 0; p < 16; ++p) mx = fmaxf(mx, gate_s[p]);
    float ge[16], ssum = 0.f;
#pragma unroll
    for (int p = 0; p < 16; ++p) { ge[p] = expf(gate_s[p] - mx); ssum += ge[p]; }
    const float inv = 1.f / ssum;
    {
        float pc = 0.f;
#pragma unroll
        for (int p = 0; p < 16; ++p) pc += ge[p] * m_s[p][tid];
        pooled_s[tid] = pc * inv;
    }
    __syncthreads();
    const int o = tid >> 5, l32 = tid & 31;
    if (o < NOUT) {
        float a = 0.f;
#pragma unroll
        for (int i = 0; i < 8; ++i) {
            const int c = l32 + 32 * i;
            a += pooled_s[c] * clsW[o * NC + c];
        }
        for (int off = 16; off; off >>= 1) a += __shfl_down(a, off);
        if (l32 == 0) outp[((size_t)g * NS + s) * NOUT + o] = a + clsb[o];
    }
}

// ---------------------------------------------------------------------------
// Generic bf16 MFMA GEMM (prep Wcomb + step 0). 64x64 tile, 256 thr.
// ---------------------------------------------------------------------------
__global__ __launch_bounds__(256) void bgemm_kernel(
    const ushortT* __restrict__ A, const ushortT* __restrict__ Bt,
    const float* __restrict__ bias, float* __restrict__ outF,
    ushortT* __restrict__ outH, int N, int K, int act)
{
    __shared__ short As[64 * 40];
    __shared__ short Bs[64 * 40];
    const int tid = threadIdx.x;
    const int lane = tid & 63, wid = tid >> 6;
    const int quad = lane >> 4, l15 = lane & 15;
    const int row0 = blockIdx.y * 64, col0 = blockIdx.x * 64;
    const int mh = (wid & 1) * 32, nh = (wid >> 1) * 32;
    const int sr = tid >> 2, skq = (tid & 3) * 8;
    const ushortT* aptr = A + (size_t)(row0 + sr) * K;
    const ushortT* bptr = Bt + (size_t)(col0 + sr) * K;

    f32x4 acc[2][2];
    for (int i = 0; i < 2; ++i)
        for (int j = 0; j < 2; ++j) acc[i][j] = (f32x4){0.f, 0.f, 0.f, 0.f};

    for (int kk = 0; kk < K; kk += 32) {
        __syncthreads();
        *(uint4*)&As[sr * 40 + skq] = *(const uint4*)(aptr + kk + skq);
        *(uint4*)&Bs[sr * 40 + skq] = *(const uint4*)(bptr + kk + skq);
        __syncthreads();
        bf16x8 af0 = *(const bf16x8*)&As[(mh + l15) * 40 + quad * 8];
        bf16x8 af1 = *(const bf16x8*)&As[(mh + 16 + l15) * 40 + quad * 8];
        bf16x8 bf0 = *(const bf16x8*)&Bs[(nh + l15) * 40 + quad * 8];
        bf16x8 bf1 = *(const bf16x8*)&Bs[(nh + 16 + l15) * 40 + quad * 8];
        acc[0][0] = MFMA16(af0, bf0, acc[0][0]);
        acc[0][1] = MFMA16(af0, bf1, acc[0][1]);
        acc[1][0] = MFMA16(af1, bf0, acc[1][0]);
        acc[1][1] = MFMA16(af1, bf1, acc[1][1]);
    }
#pragma unroll
    for (int mt = 0; mt < 2; ++mt)
#pragma unroll
        for (int nt = 0; nt < 2; ++nt) {
            const int gc = col0 + nh + nt * 16 + l15;
            const float bv = bias ? bias[gc] : 0.f;
#pragma unroll
            for (int r = 0; r < 4; ++r) {
                const int gr = row0 + mh + mt * 16 + quad * 4 + r;
                float v = acc[mt][nt][r] + bv;
                if (act) v = fmaxf(v, 0.f);
                if (outF) outF[(size_t)gr * N + gc] = v;
                if (outH) outH[(size_t)gr * N + gc] = f2b(v);
            }
        }
}

// ---------------------------------------------------------------------------
// Prep kernels
// ---------------------------------------------------------------------------
__global__ __launch_bounds__(256) void cast_kernel(const float* __restrict__ a,
                                                   ushortT* __restrict__ b, int n) {
    const int i = blockIdx.x * 256 + threadIdx.x;
    if (i < n) b[i] = f2b(a[i]);
}
__global__ __launch_bounds__(256) void gatT_kernel(const float* __restrict__ gW,
                                                   ushortT* __restrict__ gB) {
    const int idx = blockIdx.x * 256 + threadIdx.x; // < 1024*768
    const int c = idx / ND, d = idx - c * ND;
    gB[idx] = f2b(gW[(size_t)d * (NHD * NC) + c]);
}
__global__ __launch_bounds__(256) void upwT_kernel(const float* __restrict__ upW,
                                                   ushortT* __restrict__ o) {
    const int idx = blockIdx.x * 256 + threadIdx.x; // < 256*768
    const int k = idx / ND, d = idx - k * ND;
    o[idx] = f2b(upW[(size_t)d * NC + k]);
}
__global__ __launch_bounds__(256) void bcomb_kernel(const float* __restrict__ gW,
                                                    const float* __restrict__ up_b,
                                                    float* __restrict__ bc) {
    const int c = blockIdx.x * 256 + threadIdx.x;
    if (c >= NHD * NC) return;
    float a = 0.f;
    for (int d = 0; d < ND; ++d) a += up_b[d] * gW[(size_t)d * (NHD * NC) + c];
    bc[c] = a;
}
__global__ __launch_bounds__(256) void spwc_kernel(const float* __restrict__ spW,
                                                   float* __restrict__ o) {
    const int idx = blockIdx.x * 256 + threadIdx.x; // < 768*768
    const int r = idx / ND, d = idx - r * ND;
    o[idx] = spW[(size_t)r * (2 * ND) + d] + spW[(size_t)r * (2 * ND) + ND + d];
}
__global__ __launch_bounds__(256) void wus_kernel(const float* __restrict__ spWc,
                                                  const float* __restrict__ upW,
                                                  ushortT* __restrict__ WusB) {
    const int c = threadIdx.x;
    const int o0 = blockIdx.x * 16;
    float acc[16];
#pragma unroll
    for (int i = 0; i < 16; ++i) acc[i] = 0.f;
    for (int d = 0; d < ND; ++d) {
        const float u = upW[(size_t)d * NC + c];
#pragma unroll
        for (int i = 0; i < 16; ++i) acc[i] += spWc[(size_t)(o0 + i) * ND + d] * u;
    }
#pragma unroll
    for (int i = 0; i < 16; ++i) WusB[(size_t)(o0 + i) * NC + c] = f2b(acc[i]);
}
__global__ __launch_bounds__(256) void bus_kernel(const float* __restrict__ spWc,
                                                  const float* __restrict__ up_b,
                                                  const float* __restrict__ sp_b,
                                                  float* __restrict__ bus) {
    const int o = blockIdx.x * 256 + threadIdx.x;
    if (o >= ND) return;
    float a = sp_b[o];
    const float* sr = spWc + (size_t)o * ND;
    for (int d = 0; d < ND; ++d) a += sr[d] * up_b[d];
    bus[o] = a;
}
__global__ __launch_bounds__(256) void x0_kernel(const float* __restrict__ x,
                                                 ushortT* __restrict__ xb) {
    const int idx = blockIdx.x * 256 + threadIdx.x; // < 2048*768
    const int row = idx / ND, d = idx - row * ND;
    const int g = row >> 4, p = row & 15;
    xb[idx] = f2b(x[((size_t)g * (NS * NP) + p) * ND + d]);
}
__global__ __launch_bounds__(256) void zh_kernel(float* hF, ushortT* hB) {
    const int idx = blockIdx.x * 256 + threadIdx.x; // < 2048*256
    hF[idx] = 0.f;
    hB[idx] = 0;
}

// ---------------------------------------------------------------------------
extern "C" void kernel_launch(void* const* d_in, const int* in_sizes, int n_in,
                              void* d_out, int out_size, void* d_ws, size_t ws_size,
                              hipStream_t stream) {
    (void)in_sizes; (void)n_in; (void)out_size; (void)ws_size;
    const float* x       = (const float*)d_in[0];
    const float* gat_W   = (const float*)d_in[1];
    const float* att_src = (const float*)d_in[2];
    const float* att_dst = (const float*)d_in[3];
    const float* gat_b   = (const float*)d_in[4];
    const float* gru_Wih = (const float*)d_in[5];
    const float* gru_Whh = (const float*)d_in[6];
    const float* gru_bih = (const float*)d_in[7];
    const float* gru_bhh = (const float*)d_in[8];
    const float* up_W    = (const float*)d_in[9];
    const float* up_b    = (const float*)d_in[10];
    const float* sp_W    = (const float*)d_in[11];
    const float* sp_b    = (const float*)d_in[12];
    const float* att_W   = (const float*)d_in[13];
    const float* att_b   = (const float*)d_in[14];
    const float* cls_W   = (const float*)d_in[15];
    const float* cls_b   = (const float*)d_in[16];
    float* outp = (float*)d_out;

    char* w = (char*)d_ws;
    ushortT* xb    = (ushortT*)w; w += (size_t)NR * ND * 2;
    ushortT* WihB  = (ushortT*)w; w += (size_t)(3 * NC) * NC * 2;
    ushortT* WhhB  = (ushortT*)w; w += (size_t)(3 * NC) * NC * 2;
    ushortT* gatB  = (ushortT*)w; w += (size_t)(NHD * NC) * ND * 2;
    ushortT* upWT  = (ushortT*)w; w += (size_t)NC * ND * 2;
    ushortT* WcombB= (ushortT*)w; w += (size_t)(NHD * NC) * NC * 2;
    ushortT* WusB  = (ushortT*)w; w += (size_t)ND * NC * 2;
    float*   bcomb = (float*)w;   w += (size_t)(NHD * NC) * 4;
    float*   spWc  = (float*)w;   w += (size_t)ND * ND * 4;
    float*   bus   = (float*)w;   w += (size_t)ND * 4;
    float*   hF    = (float*)w;   w += (size_t)NR * NC * 4;
    ushortT* hB    = (ushortT*)w; w += (size_t)NR * NC * 2;
    ushortT* hnB   = (ushortT*)w; w += (size_t)NR * NC * 2;
    ushortT* spkB  = (ushortT*)w; w += (size_t)NG * ND * 2;
    float*   hbuf  = (float*)w;   w += (size_t)NR * (NHD * NC) * 4;
    ushortT* mB    = (ushortT*)w; w += (size_t)NR * NC * 2;

    // ---- weight prep ----
    cast_kernel<<<768, 256, 0, stream>>>(gru_Wih, WihB, 3 * NC * NC);
    cast_kernel<<<768, 256, 0, stream>>>(gru_Whh, WhhB, 3 * NC * NC);
    gatT_kernel<<<(NHD * NC * ND) / 256, 256, 0, stream>>>(gat_W, gatB);
    upwT_kernel<<<(NC * ND) / 256, 256, 0, stream>>>(up_W, upWT);
    bcomb_kernel<<<(NHD * NC) / 256, 256, 0, stream>>>(gat_W, up_b, bcomb);
    spwc_kernel<<<(ND * ND) / 256, 256, 0, stream>>>(sp_W, spWc);
    wus_kernel<<<ND / 16, 256, 0, stream>>>(spWc, up_W, WusB);
    bus_kernel<<<3, 256, 0, stream>>>(spWc, up_b, sp_b, bus);
    x0_kernel<<<(NR * ND) / 256, 256, 0, stream>>>(x, xb);
    zh_kernel<<<(NR * NC) / 256, 256, 0, stream>>>(hF, hB);
    // Wcomb[c][k] = sum_d gatW[d][c] * upW[d][k]  -> bf16 Bt layout [1024][256]
    bgemm_kernel<<<dim3(NC / 64, (NHD * NC) / 64), 256, 0, stream>>>(
        gatB, upWT, nullptr, nullptr, WcombB, NC, ND, 0);

    // ---- step 0: hbuf = x0 @ gatW; pool+classify s=0 ----
    bgemm_kernel<<<dim3((NHD * NC) / 64, NR / 64), 256, 0, stream>>>(
        xb, gatB, nullptr, hbuf, nullptr, NHD * NC, ND, 0);
    fin_kernel<<<NG, 256, 0, stream>>>(hbuf, att_src, att_dst, gat_b,
                                       att_W, att_b, cls_W, cls_b, mB, outp, 0);

    // ---- steps 1..31: three dispatches per step ----
    for (int j = 1; j < NS; ++j) {
        gru12spk_kernel<<<NG, 512, 0, stream>>>(
            mB, hB, hF, WihB, WhhB, WusB, gru_bih, gru_bhh, bus, hB, hnB, spkB);
        gatovr_kernel<<<544, 256, 0, stream>>>(
            hnB, spkB, WcombB, gatB, bcomb, hbuf);
        fin_kernel<<<NG, 256, 0, stream>>>(hbuf, att_src, att_dst, gat_b,
                                           att_W, att_b, cls_W, cls_b, mB, outp, j);
    }
}